// Round 11
// baseline (643.574 us; speedup 1.0000x reference)
//
#include <hip/hip_runtime.h>

#define B_TOT 2048
#define M_SEQ 64
#define SDIM 32
#define CDIM 8
#define LDIM 128
#define HDIM 512

#define NROWS_NEXT (B_TOT * M_SEQ)       // 131072
#define NROWS_ALL  (NROWS_NEXT + B_TOT)  // 133120

typedef short bf16x8 __attribute__((ext_vector_type(8)));
typedef float f32x4  __attribute__((ext_vector_type(4)));
typedef float f32x4v __attribute__((ext_vector_type(4)));

__device__ __forceinline__ unsigned short f2bf(float f) {
    unsigned int u = __builtin_bit_cast(unsigned int, f);
    u = u + 0x7FFFu + ((u >> 16) & 1u);   // round-to-nearest-even
    return (unsigned short)(u >> 16);
}

// bf16 h-buffer swizzle (1024B rows): XOR bits 4-7 with row&15 (4-bit).
// R8/R9 A/B: 3-bit mask -> 1.31e7 bank conflicts, 4-bit -> 6.7e4.
// Applied to the FULL byte address (add-then-xor; R2 lesson).
__device__ __forceinline__ unsigned int swz(unsigned int byte) {
    return byte ^ (((byte >> 10) & 15u) << 4);
}
// fp32 staging tile swizzle (512B rows), 4-bit
__device__ __forceinline__ unsigned int swzf(unsigned int byte) {
    return byte ^ (((byte >> 9) & 15u) << 4);
}

// ---------------------------------------------------------------------------
// Pack fp32 weight W[K][N] into bf16 fragment-major for 16x16x32 MFMA:
// out[((kt*(N/16) + nt)*64 + lane)*8 + j] = W[kt*32 + (lane>>4)*8 + j][nt*16 + (lane&15)]
// ---------------------------------------------------------------------------
__device__ __forceinline__ void pack_one16(const float* __restrict__ W, short* __restrict__ out,
                                           int e, int N) {
    int j    = e & 7;
    int lane = (e >> 3) & 63;
    int tile = e >> 9;
    int NT   = N >> 4;
    int nt   = tile % NT;
    int kt   = tile / NT;
    int k = kt * 32 + ((lane >> 4) << 3) + j;
    int n = (nt << 4) + (lane & 15);
    out[e] = (short)f2bf(W[(size_t)k * N + n]);
}

#define P_S0 16384
#define P_S1 (P_S0 + 262144)
#define P_S2 (P_S1 + 262144)
#define P_S3 (P_S2 + 65536)   // 606208 total

__global__ void pack_all(const float* __restrict__ w0, const float* __restrict__ w1,
                         const float* __restrict__ w2, const float* __restrict__ w3,
                         short* __restrict__ o0, short* __restrict__ o1,
                         short* __restrict__ o2, short* __restrict__ o3) {
    int id = blockIdx.x * 256 + threadIdx.x;
    if (id < P_S0)      pack_one16(w0, o0, id, HDIM);
    else if (id < P_S1) pack_one16(w1, o1, id - P_S0, HDIM);
    else if (id < P_S2) pack_one16(w2, o2, id - P_S1, HDIM);
    else if (id < P_S3) pack_one16(w3, o3, id - P_S2, LDIM);
}

// ---------------------------------------------------------------------------
// One MLP layer, software-pipelined kt loop (fully unrolled, static ring
// indices): A double-buffered (LDS read for kt+1 during kt's MFMAs),
// B triple-buffered (global issue for kt+2). kt-stride of packed B for
// N=512 layers: 32 tiles * 512 = 16384 shorts.
// ---------------------------------------------------------------------------
template<int KT>
__device__ __forceinline__ void layer_lds(char* hbuf, const short* __restrict__ pw,
                                          const float* __restrict__ bias,
                                          int wave, int lane) {
    const int l15 = lane & 15;
    const int lhi = lane >> 4;
    const unsigned base0 = (unsigned)(l15 * 1024 + (lhi << 4));
    const unsigned xmask = ((unsigned)l15) << 4;

    f32x4 acc[4][4];
    #pragma unroll
    for (int mt = 0; mt < 4; ++mt)
        #pragma unroll
        for (int nt = 0; nt < 4; ++nt)
            acc[mt][nt] = (f32x4){0.f, 0.f, 0.f, 0.f};

    const short* p = pw + (wave << 11) + (lane << 3);
    bf16x8 br[3][4];
    bf16x8 ar[2][4];

    #pragma unroll
    for (int nt = 0; nt < 4; ++nt) br[0][nt] = *(const bf16x8*)(p + (nt << 9));
    if (KT > 1) {
        #pragma unroll
        for (int nt = 0; nt < 4; ++nt) br[1][nt] = *(const bf16x8*)(p + 16384 + (nt << 9));
    }
    {
        const char* ab = hbuf + (base0 ^ xmask);
        #pragma unroll
        for (int mt = 0; mt < 4; ++mt) ar[0][mt] = *(const bf16x8*)(ab + mt * 16384);
    }

    #pragma unroll
    for (int kt = 0; kt < KT; ++kt) {
        if (kt + 1 < KT) {   // A for kt+1 (consumed next iteration)
            const char* ab = hbuf + ((base0 + (unsigned)(kt + 1) * 64u) ^ xmask);
            #pragma unroll
            for (int mt = 0; mt < 4; ++mt)
                ar[(kt + 1) & 1][mt] = *(const bf16x8*)(ab + mt * 16384);
        }
        if (kt + 2 < KT) {   // B for kt+2 (consumed in two iterations)
            const short* pn = p + (kt + 2) * 16384;
            #pragma unroll
            for (int nt = 0; nt < 4; ++nt)
                br[(kt + 2) % 3][nt] = *(const bf16x8*)(pn + (nt << 9));
        }
        #pragma unroll
        for (int nt = 0; nt < 4; ++nt)
            #pragma unroll
            for (int mt = 0; mt < 4; ++mt)
                acc[mt][nt] = __builtin_amdgcn_mfma_f32_16x16x32_bf16(
                    ar[kt & 1][mt], br[kt % 3][nt], acc[mt][nt], 0, 0, 0);
    }
    __syncthreads();   // all reads of hbuf done before in-place overwrite

    #pragma unroll
    for (int nt = 0; nt < 4; ++nt) {
        int colg = (wave * 4 + nt) * 16 + l15;
        float bv = bias[colg];
        #pragma unroll
        for (int mt = 0; mt < 4; ++mt) {
            #pragma unroll
            for (int r = 0; r < 4; ++r) {
                int row = mt * 16 + (lhi << 2) + r;
                float v = fmaxf(acc[mt][nt][r] + bv, 0.f);
                *(unsigned short*)(hbuf + swz((unsigned)(row * 1024 + colg * 2))) = f2bf(v);
            }
        }
    }
    __syncthreads();
}

// ---------------------------------------------------------------------------
// Fused encoder: 64 rows/block, 512 threads, 64KB LDS.
// ---------------------------------------------------------------------------
__global__ __launch_bounds__(512, 4) void encoder_kernel(
    const float* __restrict__ x_next, const float* __restrict__ x_k,
    const short* __restrict__ pw0, const short* __restrict__ pw1,
    const short* __restrict__ pw2, const short* __restrict__ pw3,
    const float* __restrict__ b0, const float* __restrict__ b1,
    const float* __restrict__ b2, const float* __restrict__ b3,
    float* __restrict__ z_target, float* __restrict__ z_k_out) {
    __shared__ __attribute__((aligned(16))) char hbuf[64 * 1024];
    const int tid  = threadIdx.x;
    const int wave = tid >> 6;
    const int lane = tid & 63;
    const int l15  = lane & 15;
    const int lhi  = lane >> 4;
    const int r0   = blockIdx.x * 64;

    const float* xin;
    float* zout;
    bool is_tgt = (r0 < NROWS_NEXT);
    if (is_tgt) {
        xin  = x_next + (size_t)r0 * SDIM;
        zout = z_target + (size_t)r0 * LDIM;
    } else {
        xin  = x_k + (size_t)(r0 - NROWS_NEXT) * SDIM;
        zout = z_k_out + (size_t)(r0 - NROWS_NEXT) * LDIM;
    }

    // stage 64x32 fp32 -> bf16 into h cols [0,32)
    {
        int row = tid >> 3;
        int c   = (tid & 7) * 4;
        float4 v = *(const float4*)(xin + row * SDIM + c);
        uint2 pk;
        pk.x = (unsigned int)f2bf(v.x) | ((unsigned int)f2bf(v.y) << 16);
        pk.y = (unsigned int)f2bf(v.z) | ((unsigned int)f2bf(v.w) << 16);
        *(uint2*)(hbuf + swz((unsigned)(row * 1024 + c * 2))) = pk;
    }
    __syncthreads();

    layer_lds<1>(hbuf, pw0, b0, wave, lane);    // 32  -> 512, relu
    layer_lds<16>(hbuf, pw1, b1, wave, lane);   // 512 -> 512, relu
    layer_lds<16>(hbuf, pw2, b2, wave, lane);   // 512 -> 512, relu

    // layer 3: 512 -> 128, no relu; same pipelining (1 ntile/wave).
    // pw3 kt-stride: 8 tiles * 512 = 4096 shorts (R10 bug: used 2048).
    {
        const unsigned base0 = (unsigned)(l15 * 1024 + (lhi << 4));
        const unsigned xmask = ((unsigned)l15) << 4;
        f32x4 acc[4];
        #pragma unroll
        for (int mt = 0; mt < 4; ++mt) acc[mt] = (f32x4){0.f, 0.f, 0.f, 0.f};

        const short* p = pw3 + (wave << 9) + (lane << 3);
        bf16x8 br[3];
        bf16x8 ar[2][4];
        br[0] = *(const bf16x8*)(p);
        br[1] = *(const bf16x8*)(p + 4096);
        {
            const char* ab = hbuf + (base0 ^ xmask);
            #pragma unroll
            for (int mt = 0; mt < 4; ++mt) ar[0][mt] = *(const bf16x8*)(ab + mt * 16384);
        }
        #pragma unroll
        for (int kt = 0; kt < 16; ++kt) {
            if (kt + 1 < 16) {
                const char* ab = hbuf + ((base0 + (unsigned)(kt + 1) * 64u) ^ xmask);
                #pragma unroll
                for (int mt = 0; mt < 4; ++mt)
                    ar[(kt + 1) & 1][mt] = *(const bf16x8*)(ab + mt * 16384);
            }
            if (kt + 2 < 16)
                br[(kt + 2) % 3] = *(const bf16x8*)(p + (kt + 2) * 4096);
            #pragma unroll
            for (int mt = 0; mt < 4; ++mt)
                acc[mt] = __builtin_amdgcn_mfma_f32_16x16x32_bf16(
                    ar[kt & 1][mt], br[kt % 3], acc[mt], 0, 0, 0);
        }
        __syncthreads();   // done reading bf16 h; reuse hbuf as [64][128] fp32

        int colg = wave * 16 + l15;
        float bv = b3[colg];
        #pragma unroll
        for (int mt = 0; mt < 4; ++mt) {
            #pragma unroll
            for (int r = 0; r < 4; ++r) {
                int row = mt * 16 + (lhi << 2) + r;
                *(float*)(hbuf + swzf((unsigned)(row * 512 + colg * 4))) = acc[mt][r] + bv;
            }
        }
        __syncthreads();

        #pragma unroll
        for (int pass = 0; pass < 4; ++pass) {
            unsigned int L = (unsigned)(pass * 512 + tid) * 16;
            f32x4v v = *(const f32x4v*)(hbuf + swzf(L));
            if (is_tgt) __builtin_nontemporal_store(v, (f32x4v*)(zout + (L >> 2)));
            else        *(f32x4v*)(zout + (L >> 2)) = v;
        }
    }
}

// ---------------------------------------------------------------------------
// Recurrence — VERBATIM round-3 version (known-good).
// ---------------------------------------------------------------------------
#define RROWS 4
__global__ __launch_bounds__(512) void recurrence_kernel(
    const float* __restrict__ zk, const float* __restrict__ u,
    const float* __restrict__ Bw, const float* __restrict__ Aw,
    float* __restrict__ zpred) {
    __shared__ float z_lds[RROWS][128];
    __shared__ float part[4][RROWS][128];
    __shared__ float Bw_lds[CDIM * 128];
    __shared__ float u_lds[RROWS * M_SEQ * CDIM];   // [b][m][c]
    const int tid   = threadIdx.x;
    const int lcol  = tid & 127;
    const int slice = tid >> 7;
    const int b0    = blockIdx.x * RROWS;

    float a[32];
    #pragma unroll
    for (int i = 0; i < 32; ++i) a[i] = Aw[(size_t)(slice * 32 + i) * 128 + lcol];

    if (tid < RROWS * 128)
        z_lds[tid >> 7][tid & 127] = zk[(size_t)(b0 + (tid >> 7)) * 128 + (tid & 127)];
    for (int id = tid; id < CDIM * 128; id += 512) Bw_lds[id] = Bw[id];
    for (int id = tid; id < RROWS * M_SEQ * CDIM; id += 512)
        u_lds[id] = u[(size_t)b0 * M_SEQ * CDIM + id];
    __syncthreads();

    for (int m = 0; m < M_SEQ; ++m) {
        #pragma unroll
        for (int b = 0; b < RROWS; ++b) {
            const float4* z4 = (const float4*)&z_lds[b][slice * 32];
            float s = 0.f;
            #pragma unroll
            for (int i = 0; i < 8; ++i) {
                float4 zv = z4[i];
                s += a[i * 4 + 0] * zv.x + a[i * 4 + 1] * zv.y +
                     a[i * 4 + 2] * zv.z + a[i * 4 + 3] * zv.w;
            }
            part[slice][b][lcol] = s;
        }
        __syncthreads();
        {
            int b = tid >> 7, l = tid & 127;
            float v = part[0][b][l] + part[1][b][l] + part[2][b][l] + part[3][b][l];
            #pragma unroll
            for (int c = 0; c < CDIM; ++c)
                v += u_lds[(b * M_SEQ + m) * CDIM + c] * Bw_lds[c * 128 + l];
            zpred[((size_t)(b0 + b) * M_SEQ + m) * 128 + l] = v;
            z_lds[b][l] = v;
        }
        __syncthreads();
    }
}

// ---------------------------------------------------------------------------
// Decoder — VERBATIM round-3 version (8 rows x 32 cols per 256-thread block).
// ---------------------------------------------------------------------------
__global__ __launch_bounds__(256) void decoder_kernel(
    const float* __restrict__ zpred, const float* __restrict__ Cw,
    const float* __restrict__ Cb, float* __restrict__ xpred) {
    __shared__ float C_lds[LDIM * SDIM];
    __shared__ float cb_lds[SDIM];
    const int tid = threadIdx.x;
    for (int id = tid; id < LDIM * SDIM; id += 256) C_lds[id] = Cw[id];
    if (tid < SDIM) cb_lds[tid] = Cb[tid];
    __syncthreads();

    const int col = tid & 31;
    const size_t row = (size_t)blockIdx.x * 8 + (tid >> 5);
    const float4* z4 = (const float4*)(zpred + row * LDIM);
    float s = cb_lds[col];
    #pragma unroll
    for (int i = 0; i < 32; ++i) {
        float4 zv = z4[i];
        s += zv.x * C_lds[(i * 4 + 0) * SDIM + col] + zv.y * C_lds[(i * 4 + 1) * SDIM + col] +
             zv.z * C_lds[(i * 4 + 2) * SDIM + col] + zv.w * C_lds[(i * 4 + 3) * SDIM + col];
    }
    xpred[row * SDIM + col] = s;
}

extern "C" void kernel_launch(void* const* d_in, const int* in_sizes, int n_in,
                              void* d_out, int out_size, void* d_ws, size_t ws_size,
                              hipStream_t stream) {
    const float* x_k    = (const float*)d_in[0];
    const float* u_seq  = (const float*)d_in[1];
    const float* x_next = (const float*)d_in[2];
    const float* w0 = (const float*)d_in[3];  const float* b0 = (const float*)d_in[4];
    const float* w1 = (const float*)d_in[5];  const float* b1 = (const float*)d_in[6];
    const float* w2 = (const float*)d_in[7];  const float* b2 = (const float*)d_in[8];
    const float* w3 = (const float*)d_in[9];  const float* b3 = (const float*)d_in[10];
    const float* A_w = (const float*)d_in[11];
    const float* B_w = (const float*)d_in[12];
    const float* C_w = (const float*)d_in[13];
    const float* C_b = (const float*)d_in[14];

    float* out    = (float*)d_out;
    float* z_pred = out;                                   // 2048*64*128
    float* x_pred = out + (size_t)NROWS_NEXT * LDIM;       // 2048*64*32
    float* z_tgt  = x_pred + (size_t)NROWS_NEXT * SDIM;    // 2048*64*128

    char* ws = (char*)d_ws;
    short* pw0 = (short*)(ws);                             // 32 KB
    short* pw1 = (short*)(ws + 32768);                     // 512 KB
    short* pw2 = (short*)(ws + 32768 + 524288);            // 512 KB
    short* pw3 = (short*)(ws + 32768 + 2 * 524288);        // 128 KB
    float* z_k_buf = (float*)(ws + 32768 + 2 * 524288 + 131072);  // 1 MB

    pack_all<<<(P_S3 + 255) / 256, 256, 0, stream>>>(w0, w1, w2, w3, pw0, pw1, pw2, pw3);

    encoder_kernel<<<NROWS_ALL / 64, 512, 0, stream>>>(
        x_next, x_k, pw0, pw1, pw2, pw3, b0, b1, b2, b3, z_tgt, z_k_buf);

    recurrence_kernel<<<B_TOT / RROWS, 512, 0, stream>>>(z_k_buf, u_seq, B_w, A_w, z_pred);

    decoder_kernel<<<NROWS_NEXT / 8, 256, 0, stream>>>(z_pred, C_w, C_b, x_pred);
}

// Round 12
// 505.285 us; speedup vs baseline: 1.2737x; 1.2737x over previous
//
#include <hip/hip_runtime.h>

#define B_TOT 2048
#define M_SEQ 64
#define SDIM 32
#define CDIM 8
#define LDIM 128
#define HDIM 512

#define NROWS_NEXT (B_TOT * M_SEQ)       // 131072
#define NROWS_ALL  (NROWS_NEXT + B_TOT)  // 133120

typedef short bf16x8 __attribute__((ext_vector_type(8)));
typedef float f32x4  __attribute__((ext_vector_type(4)));
typedef float f32x4v __attribute__((ext_vector_type(4)));

__device__ __forceinline__ unsigned short f2bf(float f) {
    unsigned int u = __builtin_bit_cast(unsigned int, f);
    u = u + 0x7FFFu + ((u >> 16) & 1u);   // round-to-nearest-even
    return (unsigned short)(u >> 16);
}

// bf16 h-buffer swizzle (1024B rows): XOR bits 4-7 with row&15 (4-bit).
// Applied to the FULL byte address (add-then-xor; R2 lesson).
__device__ __forceinline__ unsigned int swz(unsigned int byte) {
    return byte ^ (((byte >> 10) & 15u) << 4);
}
// fp32 staging tile swizzle (512B rows), 4-bit
__device__ __forceinline__ unsigned int swzf(unsigned int byte) {
    return byte ^ (((byte >> 9) & 15u) << 4);
}

// ---------------------------------------------------------------------------
// Pack fp32 weight W[K][N] into bf16 fragment-major for 16x16x32 MFMA.
// ---------------------------------------------------------------------------
__device__ __forceinline__ void pack_one16(const float* __restrict__ W, short* __restrict__ out,
                                           int e, int N) {
    int j    = e & 7;
    int lane = (e >> 3) & 63;
    int tile = e >> 9;
    int NT   = N >> 4;
    int nt   = tile % NT;
    int kt   = tile / NT;
    int k = kt * 32 + ((lane >> 4) << 3) + j;
    int n = (nt << 4) + (lane & 15);
    out[e] = (short)f2bf(W[(size_t)k * N + n]);
}

#define P_S0 16384
#define P_S1 (P_S0 + 262144)
#define P_S2 (P_S1 + 262144)
#define P_S3 (P_S2 + 65536)   // 606208 total

__global__ void pack_all(const float* __restrict__ w0, const float* __restrict__ w1,
                         const float* __restrict__ w2, const float* __restrict__ w3,
                         short* __restrict__ o0, short* __restrict__ o1,
                         short* __restrict__ o2, short* __restrict__ o3) {
    int id = blockIdx.x * 256 + threadIdx.x;
    if (id < P_S0)      pack_one16(w0, o0, id, HDIM);
    else if (id < P_S1) pack_one16(w1, o1, id - P_S0, HDIM);
    else if (id < P_S2) pack_one16(w2, o2, id - P_S1, HDIM);
    else if (id < P_S3) pack_one16(w3, o3, id - P_S2, LDIM);
}

// ---------------------------------------------------------------------------
// One MLP layer — R9-EXACT (348us measured; R11's deeper rings spill: regs
// 64 acc + 48 B-ring + 32 A-ring > 128 cap -> +100MB scratch WRITE_SIZE).
// ---------------------------------------------------------------------------
__device__ __forceinline__ void layer_lds(char* hbuf, const short* __restrict__ pw,
                                          const float* __restrict__ bias,
                                          int ktCount, int wave, int lane) {
    const int l15 = lane & 15;
    const int lhi = lane >> 4;
    const unsigned base0 = (unsigned)(l15 * 1024 + (lhi << 4));
    const unsigned xmask = ((unsigned)l15) << 4;

    f32x4 acc[4][4];
    #pragma unroll
    for (int mt = 0; mt < 4; ++mt)
        #pragma unroll
        for (int nt = 0; nt < 4; ++nt)
            acc[mt][nt] = (f32x4){0.f, 0.f, 0.f, 0.f};

    const short* p = pw + (wave << 11) + (lane << 3);
    bf16x8 bcur[4];
    #pragma unroll
    for (int nt = 0; nt < 4; ++nt) bcur[nt] = *(const bf16x8*)(p + (nt << 9));

    for (int kt = 0; kt < ktCount; ++kt) {
        bf16x8 bnext[4];
        if (kt + 1 < ktCount) {
            const short* pn = p + 16384;
            #pragma unroll
            for (int nt = 0; nt < 4; ++nt) bnext[nt] = *(const bf16x8*)(pn + (nt << 9));
        }
        const char* abase = hbuf + ((base0 + (unsigned)kt * 64u) ^ xmask);
        bf16x8 a[4];
        #pragma unroll
        for (int mt = 0; mt < 4; ++mt)
            a[mt] = *(const bf16x8*)(abase + mt * 16384);
        #pragma unroll
        for (int nt = 0; nt < 4; ++nt)
            #pragma unroll
            for (int mt = 0; mt < 4; ++mt)
                acc[mt][nt] = __builtin_amdgcn_mfma_f32_16x16x32_bf16(a[mt], bcur[nt], acc[mt][nt], 0, 0, 0);
        p += 16384;
        if (kt + 1 < ktCount) {
            #pragma unroll
            for (int nt = 0; nt < 4; ++nt) bcur[nt] = bnext[nt];
        }
    }
    __syncthreads();

    #pragma unroll
    for (int nt = 0; nt < 4; ++nt) {
        int colg = (wave * 4 + nt) * 16 + l15;
        float bv = bias[colg];
        #pragma unroll
        for (int mt = 0; mt < 4; ++mt) {
            #pragma unroll
            for (int r = 0; r < 4; ++r) {
                int row = mt * 16 + (lhi << 2) + r;
                float v = fmaxf(acc[mt][nt][r] + bv, 0.f);
                *(unsigned short*)(hbuf + swz((unsigned)(row * 1024 + colg * 2))) = f2bf(v);
            }
        }
    }
    __syncthreads();
}

// ---------------------------------------------------------------------------
// Fused encoder — R9-EXACT.
// ---------------------------------------------------------------------------
__global__ __launch_bounds__(512, 4) void encoder_kernel(
    const float* __restrict__ x_next, const float* __restrict__ x_k,
    const short* __restrict__ pw0, const short* __restrict__ pw1,
    const short* __restrict__ pw2, const short* __restrict__ pw3,
    const float* __restrict__ b0, const float* __restrict__ b1,
    const float* __restrict__ b2, const float* __restrict__ b3,
    float* __restrict__ z_target, float* __restrict__ z_k_out) {
    __shared__ __attribute__((aligned(16))) char hbuf[64 * 1024];
    const int tid  = threadIdx.x;
    const int wave = tid >> 6;
    const int lane = tid & 63;
    const int l15  = lane & 15;
    const int lhi  = lane >> 4;
    const int r0   = blockIdx.x * 64;

    const float* xin;
    float* zout;
    bool is_tgt = (r0 < NROWS_NEXT);
    if (is_tgt) {
        xin  = x_next + (size_t)r0 * SDIM;
        zout = z_target + (size_t)r0 * LDIM;
    } else {
        xin  = x_k + (size_t)(r0 - NROWS_NEXT) * SDIM;
        zout = z_k_out + (size_t)(r0 - NROWS_NEXT) * LDIM;
    }

    // stage 64x32 fp32 -> bf16 into h cols [0,32)
    {
        int row = tid >> 3;
        int c   = (tid & 7) * 4;
        float4 v = *(const float4*)(xin + row * SDIM + c);
        uint2 pk;
        pk.x = (unsigned int)f2bf(v.x) | ((unsigned int)f2bf(v.y) << 16);
        pk.y = (unsigned int)f2bf(v.z) | ((unsigned int)f2bf(v.w) << 16);
        *(uint2*)(hbuf + swz((unsigned)(row * 1024 + c * 2))) = pk;
    }
    __syncthreads();

    layer_lds(hbuf, pw0, b0, 1, wave, lane);    // 32  -> 512, relu
    layer_lds(hbuf, pw1, b1, 16, wave, lane);   // 512 -> 512, relu
    layer_lds(hbuf, pw2, b2, 16, wave, lane);   // 512 -> 512, relu

    // layer 3: 512 -> 128, no relu; fp32 LDS staging then coalesced stores.
    {
        const unsigned base0 = (unsigned)(l15 * 1024 + (lhi << 4));
        const unsigned xmask = ((unsigned)l15) << 4;
        f32x4 acc[4];
        #pragma unroll
        for (int mt = 0; mt < 4; ++mt) acc[mt] = (f32x4){0.f, 0.f, 0.f, 0.f};

        const short* p = pw3 + (wave << 9) + (lane << 3);
        bf16x8 bcur = *(const bf16x8*)(p);
        for (int kt = 0; kt < 16; ++kt) {
            bf16x8 bnext;
            if (kt < 15) bnext = *(const bf16x8*)(p + 4096);
            const char* abase = hbuf + ((base0 + (unsigned)kt * 64u) ^ xmask);
            bf16x8 a[4];
            #pragma unroll
            for (int mt = 0; mt < 4; ++mt)
                a[mt] = *(const bf16x8*)(abase + mt * 16384);
            #pragma unroll
            for (int mt = 0; mt < 4; ++mt)
                acc[mt] = __builtin_amdgcn_mfma_f32_16x16x32_bf16(a[mt], bcur, acc[mt], 0, 0, 0);
            p += 4096;
            if (kt < 15) bcur = bnext;
        }
        __syncthreads();   // done reading bf16 h; reuse hbuf as [64][128] fp32

        int colg = wave * 16 + l15;
        float bv = b3[colg];
        #pragma unroll
        for (int mt = 0; mt < 4; ++mt) {
            #pragma unroll
            for (int r = 0; r < 4; ++r) {
                int row = mt * 16 + (lhi << 2) + r;
                *(float*)(hbuf + swzf((unsigned)(row * 512 + colg * 4))) = acc[mt][r] + bv;
            }
        }
        __syncthreads();

        #pragma unroll
        for (int pass = 0; pass < 4; ++pass) {
            unsigned int L = (unsigned)(pass * 512 + tid) * 16;
            f32x4v v = *(const f32x4v*)(hbuf + swzf(L));
            if (is_tgt) __builtin_nontemporal_store(v, (f32x4v*)(zout + (L >> 2)));
            else        *(f32x4v*)(zout + (L >> 2)) = v;
        }
    }
}

// ---------------------------------------------------------------------------
// Recurrence WITH FUSED DECODER. R3-verbatim recurrence core; after each
// step's z-update barrier, waves 0-1 (tid<128, wave-uniform) compute the
// 4x32 x_pred outputs for step m from z_lds (broadcast) x C_lds
// (conflict-free: col spans 32 banks). Race-safe without an extra barrier:
// the next z_lds overwrite is behind the next step's barrier, which these
// threads reach only after their reads.
// ---------------------------------------------------------------------------
#define RROWS 4
__global__ __launch_bounds__(512) void recurrence_kernel(
    const float* __restrict__ zk, const float* __restrict__ u,
    const float* __restrict__ Bw, const float* __restrict__ Aw,
    const float* __restrict__ Cw, const float* __restrict__ Cb,
    float* __restrict__ zpred, float* __restrict__ xpred) {
    __shared__ float z_lds[RROWS][128];
    __shared__ float part[4][RROWS][128];
    __shared__ float Bw_lds[CDIM * 128];
    __shared__ float u_lds[RROWS * M_SEQ * CDIM];   // [b][m][c]
    __shared__ float C_lds[LDIM * SDIM];            // [l][col], 16KB
    __shared__ float cb_lds[SDIM];
    const int tid   = threadIdx.x;
    const int lcol  = tid & 127;
    const int slice = tid >> 7;
    const int b0    = blockIdx.x * RROWS;

    float a[32];
    #pragma unroll
    for (int i = 0; i < 32; ++i) a[i] = Aw[(size_t)(slice * 32 + i) * 128 + lcol];

    if (tid < RROWS * 128)
        z_lds[tid >> 7][tid & 127] = zk[(size_t)(b0 + (tid >> 7)) * 128 + (tid & 127)];
    for (int id = tid; id < CDIM * 128; id += 512) Bw_lds[id] = Bw[id];
    for (int id = tid; id < RROWS * M_SEQ * CDIM; id += 512)
        u_lds[id] = u[(size_t)b0 * M_SEQ * CDIM + id];
    for (int id = tid; id < LDIM * SDIM; id += 512) C_lds[id] = Cw[id];
    if (tid < SDIM) cb_lds[tid] = Cb[tid];
    __syncthreads();

    for (int m = 0; m < M_SEQ; ++m) {
        #pragma unroll
        for (int b = 0; b < RROWS; ++b) {
            const float4* z4 = (const float4*)&z_lds[b][slice * 32];
            float s = 0.f;
            #pragma unroll
            for (int i = 0; i < 8; ++i) {
                float4 zv = z4[i];
                s += a[i * 4 + 0] * zv.x + a[i * 4 + 1] * zv.y +
                     a[i * 4 + 2] * zv.z + a[i * 4 + 3] * zv.w;
            }
            part[slice][b][lcol] = s;
        }
        __syncthreads();
        {
            int b = tid >> 7, l = tid & 127;
            float v = part[0][b][l] + part[1][b][l] + part[2][b][l] + part[3][b][l];
            #pragma unroll
            for (int c = 0; c < CDIM; ++c)
                v += u_lds[(b * M_SEQ + m) * CDIM + c] * Bw_lds[c * 128 + l];
            zpred[((size_t)(b0 + b) * M_SEQ + m) * 128 + l] = v;
            z_lds[b][l] = v;
        }
        __syncthreads();
        // fused decoder: x_pred[b0+b, m, :] = z_lds[b] @ C + cb
        if (tid < 128) {
            int b = tid >> 5, col = tid & 31;
            float s = cb_lds[col];
            const float4* z4 = (const float4*)&z_lds[b][0];
            #pragma unroll
            for (int i = 0; i < 32; ++i) {
                float4 zv = z4[i];
                s += zv.x * C_lds[(i * 4 + 0) * SDIM + col] +
                     zv.y * C_lds[(i * 4 + 1) * SDIM + col] +
                     zv.z * C_lds[(i * 4 + 2) * SDIM + col] +
                     zv.w * C_lds[(i * 4 + 3) * SDIM + col];
            }
            xpred[((size_t)(b0 + b) * M_SEQ + m) * SDIM + col] = s;
        }
    }
}

extern "C" void kernel_launch(void* const* d_in, const int* in_sizes, int n_in,
                              void* d_out, int out_size, void* d_ws, size_t ws_size,
                              hipStream_t stream) {
    const float* x_k    = (const float*)d_in[0];
    const float* u_seq  = (const float*)d_in[1];
    const float* x_next = (const float*)d_in[2];
    const float* w0 = (const float*)d_in[3];  const float* b0 = (const float*)d_in[4];
    const float* w1 = (const float*)d_in[5];  const float* b1 = (const float*)d_in[6];
    const float* w2 = (const float*)d_in[7];  const float* b2 = (const float*)d_in[8];
    const float* w3 = (const float*)d_in[9];  const float* b3 = (const float*)d_in[10];
    const float* A_w = (const float*)d_in[11];
    const float* B_w = (const float*)d_in[12];
    const float* C_w = (const float*)d_in[13];
    const float* C_b = (const float*)d_in[14];

    float* out    = (float*)d_out;
    float* z_pred = out;                                   // 2048*64*128
    float* x_pred = out + (size_t)NROWS_NEXT * LDIM;       // 2048*64*32
    float* z_tgt  = x_pred + (size_t)NROWS_NEXT * SDIM;    // 2048*64*128

    char* ws = (char*)d_ws;
    short* pw0 = (short*)(ws);                             // 32 KB
    short* pw1 = (short*)(ws + 32768);                     // 512 KB
    short* pw2 = (short*)(ws + 32768 + 524288);            // 512 KB
    short* pw3 = (short*)(ws + 32768 + 2 * 524288);        // 128 KB
    float* z_k_buf = (float*)(ws + 32768 + 2 * 524288 + 131072);  // 1 MB

    pack_all<<<(P_S3 + 255) / 256, 256, 0, stream>>>(w0, w1, w2, w3, pw0, pw1, pw2, pw3);

    encoder_kernel<<<NROWS_ALL / 64, 512, 0, stream>>>(
        x_next, x_k, pw0, pw1, pw2, pw3, b0, b1, b2, b3, z_tgt, z_k_buf);

    recurrence_kernel<<<B_TOT / RROWS, 512, 0, stream>>>(
        z_k_buf, u_seq, B_w, A_w, C_w, C_b, z_pred, x_pred);
}

// Round 13
// 446.129 us; speedup vs baseline: 1.4426x; 1.1326x over previous
//
#include <hip/hip_runtime.h>

#define B_TOT 2048
#define M_SEQ 64
#define SDIM 32
#define CDIM 8
#define LDIM 128
#define HDIM 512

#define NROWS_NEXT (B_TOT * M_SEQ)       // 131072
#define NROWS_ALL  (NROWS_NEXT + B_TOT)  // 133120

typedef short bf16x8 __attribute__((ext_vector_type(8)));
typedef float f32x4  __attribute__((ext_vector_type(4)));
typedef float f32x4v __attribute__((ext_vector_type(4)));

__device__ __forceinline__ unsigned short f2bf(float f) {
    unsigned int u = __builtin_bit_cast(unsigned int, f);
    u = u + 0x7FFFu + ((u >> 16) & 1u);   // round-to-nearest-even
    return (unsigned short)(u >> 16);
}

// bf16 h-buffer swizzle (1024B rows): XOR bits 4-7 with row&15 (4-bit).
__device__ __forceinline__ unsigned int swz(unsigned int byte) {
    return byte ^ (((byte >> 10) & 15u) << 4);
}
// fp32 staging tile swizzle (512B rows), 4-bit
__device__ __forceinline__ unsigned int swzf(unsigned int byte) {
    return byte ^ (((byte >> 9) & 15u) << 4);
}

// ---------------------------------------------------------------------------
// Pack fp32 weight W[K][N] into bf16 fragment-major for 16x16x32 MFMA.
// ---------------------------------------------------------------------------
__device__ __forceinline__ void pack_one16(const float* __restrict__ W, short* __restrict__ out,
                                           int e, int N) {
    int j    = e & 7;
    int lane = (e >> 3) & 63;
    int tile = e >> 9;
    int NT   = N >> 4;
    int nt   = tile % NT;
    int kt   = tile / NT;
    int k = kt * 32 + ((lane >> 4) << 3) + j;
    int n = (nt << 4) + (lane & 15);
    out[e] = (short)f2bf(W[(size_t)k * N + n]);
}

#define P_S0 16384
#define P_S1 (P_S0 + 262144)
#define P_S2 (P_S1 + 262144)
#define P_S3 (P_S2 + 65536)   // 606208 total

__global__ void pack_all(const float* __restrict__ w0, const float* __restrict__ w1,
                         const float* __restrict__ w2, const float* __restrict__ w3,
                         short* __restrict__ o0, short* __restrict__ o1,
                         short* __restrict__ o2, short* __restrict__ o3) {
    int id = blockIdx.x * 256 + threadIdx.x;
    if (id < P_S0)      pack_one16(w0, o0, id, HDIM);
    else if (id < P_S1) pack_one16(w1, o1, id - P_S0, HDIM);
    else if (id < P_S2) pack_one16(w2, o2, id - P_S1, HDIM);
    else if (id < P_S3) pack_one16(w3, o3, id - P_S2, LDIM);
}

// ---------------------------------------------------------------------------
// O = X @ Y for 128x128 fp32 (used for A2 = A @ A). 128 blocks x 128 threads.
// ---------------------------------------------------------------------------
__global__ __launch_bounds__(128) void mm128(const float* __restrict__ X,
                                             const float* __restrict__ Y,
                                             float* __restrict__ O) {
    int r = blockIdx.x, c = threadIdx.x;
    float s = 0.f;
    for (int k = 0; k < 128; ++k) s += X[r * 128 + k] * Y[k * 128 + c];
    O[r * 128 + c] = s;
}

// ---------------------------------------------------------------------------
// One MLP layer — R9-EXACT (349us measured; deeper rings spill).
// ---------------------------------------------------------------------------
__device__ __forceinline__ void layer_lds(char* hbuf, const short* __restrict__ pw,
                                          const float* __restrict__ bias,
                                          int ktCount, int wave, int lane) {
    const int l15 = lane & 15;
    const int lhi = lane >> 4;
    const unsigned base0 = (unsigned)(l15 * 1024 + (lhi << 4));
    const unsigned xmask = ((unsigned)l15) << 4;

    f32x4 acc[4][4];
    #pragma unroll
    for (int mt = 0; mt < 4; ++mt)
        #pragma unroll
        for (int nt = 0; nt < 4; ++nt)
            acc[mt][nt] = (f32x4){0.f, 0.f, 0.f, 0.f};

    const short* p = pw + (wave << 11) + (lane << 3);
    bf16x8 bcur[4];
    #pragma unroll
    for (int nt = 0; nt < 4; ++nt) bcur[nt] = *(const bf16x8*)(p + (nt << 9));

    for (int kt = 0; kt < ktCount; ++kt) {
        bf16x8 bnext[4];
        if (kt + 1 < ktCount) {
            const short* pn = p + 16384;
            #pragma unroll
            for (int nt = 0; nt < 4; ++nt) bnext[nt] = *(const bf16x8*)(pn + (nt << 9));
        }
        const char* abase = hbuf + ((base0 + (unsigned)kt * 64u) ^ xmask);
        bf16x8 a[4];
        #pragma unroll
        for (int mt = 0; mt < 4; ++mt)
            a[mt] = *(const bf16x8*)(abase + mt * 16384);
        #pragma unroll
        for (int nt = 0; nt < 4; ++nt)
            #pragma unroll
            for (int mt = 0; mt < 4; ++mt)
                acc[mt][nt] = __builtin_amdgcn_mfma_f32_16x16x32_bf16(a[mt], bcur[nt], acc[mt][nt], 0, 0, 0);
        p += 16384;
        if (kt + 1 < ktCount) {
            #pragma unroll
            for (int nt = 0; nt < 4; ++nt) bcur[nt] = bnext[nt];
        }
    }
    __syncthreads();

    #pragma unroll
    for (int nt = 0; nt < 4; ++nt) {
        int colg = (wave * 4 + nt) * 16 + l15;
        float bv = bias[colg];
        #pragma unroll
        for (int mt = 0; mt < 4; ++mt) {
            #pragma unroll
            for (int r = 0; r < 4; ++r) {
                int row = mt * 16 + (lhi << 2) + r;
                float v = fmaxf(acc[mt][nt][r] + bv, 0.f);
                *(unsigned short*)(hbuf + swz((unsigned)(row * 1024 + colg * 2))) = f2bf(v);
            }
        }
    }
    __syncthreads();
}

// ---------------------------------------------------------------------------
// Fused encoder — R9-EXACT.
// ---------------------------------------------------------------------------
__global__ __launch_bounds__(512, 4) void encoder_kernel(
    const float* __restrict__ x_next, const float* __restrict__ x_k,
    const short* __restrict__ pw0, const short* __restrict__ pw1,
    const short* __restrict__ pw2, const short* __restrict__ pw3,
    const float* __restrict__ b0, const float* __restrict__ b1,
    const float* __restrict__ b2, const float* __restrict__ b3,
    float* __restrict__ z_target, float* __restrict__ z_k_out) {
    __shared__ __attribute__((aligned(16))) char hbuf[64 * 1024];
    const int tid  = threadIdx.x;
    const int wave = tid >> 6;
    const int lane = tid & 63;
    const int l15  = lane & 15;
    const int lhi  = lane >> 4;
    const int r0   = blockIdx.x * 64;

    const float* xin;
    float* zout;
    bool is_tgt = (r0 < NROWS_NEXT);
    if (is_tgt) {
        xin  = x_next + (size_t)r0 * SDIM;
        zout = z_target + (size_t)r0 * LDIM;
    } else {
        xin  = x_k + (size_t)(r0 - NROWS_NEXT) * SDIM;
        zout = z_k_out + (size_t)(r0 - NROWS_NEXT) * LDIM;
    }

    {
        int row = tid >> 3;
        int c   = (tid & 7) * 4;
        float4 v = *(const float4*)(xin + row * SDIM + c);
        uint2 pk;
        pk.x = (unsigned int)f2bf(v.x) | ((unsigned int)f2bf(v.y) << 16);
        pk.y = (unsigned int)f2bf(v.z) | ((unsigned int)f2bf(v.w) << 16);
        *(uint2*)(hbuf + swz((unsigned)(row * 1024 + c * 2))) = pk;
    }
    __syncthreads();

    layer_lds(hbuf, pw0, b0, 1, wave, lane);    // 32  -> 512, relu
    layer_lds(hbuf, pw1, b1, 16, wave, lane);   // 512 -> 512, relu
    layer_lds(hbuf, pw2, b2, 16, wave, lane);   // 512 -> 512, relu

    {
        const unsigned base0 = (unsigned)(l15 * 1024 + (lhi << 4));
        const unsigned xmask = ((unsigned)l15) << 4;
        f32x4 acc[4];
        #pragma unroll
        for (int mt = 0; mt < 4; ++mt) acc[mt] = (f32x4){0.f, 0.f, 0.f, 0.f};

        const short* p = pw3 + (wave << 9) + (lane << 3);
        bf16x8 bcur = *(const bf16x8*)(p);
        for (int kt = 0; kt < 16; ++kt) {
            bf16x8 bnext;
            if (kt < 15) bnext = *(const bf16x8*)(p + 4096);
            const char* abase = hbuf + ((base0 + (unsigned)kt * 64u) ^ xmask);
            bf16x8 a[4];
            #pragma unroll
            for (int mt = 0; mt < 4; ++mt)
                a[mt] = *(const bf16x8*)(abase + mt * 16384);
            #pragma unroll
            for (int mt = 0; mt < 4; ++mt)
                acc[mt] = __builtin_amdgcn_mfma_f32_16x16x32_bf16(a[mt], bcur, acc[mt], 0, 0, 0);
            p += 4096;
            if (kt < 15) bcur = bnext;
        }
        __syncthreads();

        int colg = wave * 16 + l15;
        float bv = b3[colg];
        #pragma unroll
        for (int mt = 0; mt < 4; ++mt) {
            #pragma unroll
            for (int r = 0; r < 4; ++r) {
                int row = mt * 16 + (lhi << 2) + r;
                *(float*)(hbuf + swzf((unsigned)(row * 512 + colg * 4))) = acc[mt][r] + bv;
            }
        }
        __syncthreads();

        #pragma unroll
        for (int pass = 0; pass < 4; ++pass) {
            unsigned int L = (unsigned)(pass * 512 + tid) * 16;
            f32x4v v = *(const f32x4v*)(hbuf + swzf(L));
            if (is_tgt) __builtin_nontemporal_store(v, (f32x4v*)(zout + (L >> 2)));
            else        *(f32x4v*)(zout + (L >> 2)) = v;
        }
    }
}

// ---------------------------------------------------------------------------
// 2-step unrolled recurrence + fused decoder.
//   z[m0]   = z_in A  + u[m0] B
//   z[m0+1] = z_in A2 + u[m0] (B A) + u[m0+1] B
// Thread (slice=tid>>7, col=tid&127) holds A[ks,col] and A2[ks,col] slices
// (64 regs) + ba[16] = {B[.,col], (BA)[.,col]}. Per round z is read ONCE for
// two steps (halves the LDS z-read invariant). Decoder for round r-1 runs in
// round r's phase-A slot (disjoint arrays: zout vs z_lds). 2 barriers/round.
// ---------------------------------------------------------------------------
#define RR4 4
__global__ __launch_bounds__(512, 4) void recurrence2_kernel(
    const float* __restrict__ zk, const float* __restrict__ u,
    const float* __restrict__ Bw, const float* __restrict__ Aw,
    const float* __restrict__ A2, const float* __restrict__ Cw,
    const float* __restrict__ Cb,
    float* __restrict__ zpred, float* __restrict__ xpred) {
    __shared__ float z_lds[RR4][128];            // 2 KB
    __shared__ float part[4][8][128];            // 16 KB
    __shared__ float zoutb[2][RR4][128];         // 4 KB
    __shared__ float u_lds[RR4 * M_SEQ * CDIM];  // 8 KB
    __shared__ float Bw_lds[CDIM * 128];         // 4 KB
    __shared__ float Ct_lds[32 * 132];           // 16.5 KB, C transposed, pad 132
    __shared__ float cb_lds[SDIM];
    const int tid   = threadIdx.x;
    const int col   = tid & 127;
    const int slice = tid >> 7;
    const int b0    = blockIdx.x * RR4;

    float a1[32], a2r[32], ba[16];
    #pragma unroll
    for (int i = 0; i < 32; ++i) {
        a1[i]  = Aw[(size_t)(slice * 32 + i) * 128 + col];
        a2r[i] = A2[(size_t)(slice * 32 + i) * 128 + col];
    }

    if (tid < RR4 * 128)
        z_lds[tid >> 7][tid & 127] = zk[(size_t)(b0 + (tid >> 7)) * 128 + (tid & 127)];
    for (int id = tid; id < CDIM * 128; id += 512) Bw_lds[id] = Bw[id];
    for (int id = tid; id < RR4 * M_SEQ * CDIM; id += 512)
        u_lds[id] = u[(size_t)b0 * M_SEQ * CDIM + id];
    for (int id = tid; id < 128 * 32; id += 512) {
        int k = id >> 5, c = id & 31;
        Ct_lds[c * 132 + k] = Cw[id];            // Cw[k*32+c] coalesced
    }
    if (tid < SDIM) cb_lds[tid] = Cb[tid];
    __syncthreads();

    // BA = B @ A via part-reduce (prologue only)
    #pragma unroll
    for (int c = 0; c < 8; ++c) {
        float s = 0.f;
        #pragma unroll
        for (int kk = 0; kk < 32; ++kk) s += Bw_lds[c * 128 + slice * 32 + kk] * a1[kk];
        part[slice][c][col] = s;
    }
    __syncthreads();
    #pragma unroll
    for (int c = 0; c < 8; ++c) {
        ba[c]     = Bw_lds[c * 128 + col];
        ba[8 + c] = part[0][c][col] + part[1][c][col] + part[2][c][col] + part[3][c][col];
    }
    __syncthreads();

    for (int r = 0; r < 32; ++r) {
        const int m0 = 2 * r;
        // ---- phase A: ph1 partials (+ decoder for round r-1) ----
        #pragma unroll
        for (int b = 0; b < RR4; ++b) {
            const float4* z4 = (const float4*)&z_lds[b][slice * 32];
            float p1 = 0.f, p2 = 0.f;
            #pragma unroll
            for (int i = 0; i < 8; ++i) {
                float4 zv = z4[i];
                p1 += a1[i*4+0]*zv.x + a1[i*4+1]*zv.y + a1[i*4+2]*zv.z + a1[i*4+3]*zv.w;
                p2 += a2r[i*4+0]*zv.x + a2r[i*4+1]*zv.y + a2r[i*4+2]*zv.z + a2r[i*4+3]*zv.w;
            }
            part[slice][b * 2 + 0][col] = p1;
            part[slice][b * 2 + 1][col] = p2;
        }
        if (r > 0 && tid < 256) {
            const int mprev = 2 * (r - 1);
            int sb = tid >> 5, c32 = tid & 31;
            int s = sb >> 2, b = sb & 3;
            float acc = cb_lds[c32];
            const float4* z4 = (const float4*)&zoutb[s][b][0];
            const float4* c4 = (const float4*)&Ct_lds[c32 * 132];
            #pragma unroll
            for (int i = 0; i < 32; ++i) {
                float4 zv = z4[i], cv = c4[i];
                acc += zv.x*cv.x + zv.y*cv.y + zv.z*cv.z + zv.w*cv.w;
            }
            __builtin_nontemporal_store(acc,
                xpred + ((size_t)(b0 + b) * M_SEQ + (mprev + s)) * SDIM + c32);
        }
        __syncthreads();
        // ---- phase B: reduce + u corrections + outputs ----
        {
            const int b = slice;
            float v0 = part[0][b*2+0][col] + part[1][b*2+0][col] + part[2][b*2+0][col] + part[3][b*2+0][col];
            float v1 = part[0][b*2+1][col] + part[1][b*2+1][col] + part[2][b*2+1][col] + part[3][b*2+1][col];
            const float4* uu0 = (const float4*)&u_lds[(b * M_SEQ + m0) * CDIM];
            float4 ua = uu0[0], ub = uu0[1];
            v0 += ua.x*ba[0] + ua.y*ba[1] + ua.z*ba[2] + ua.w*ba[3]
                + ub.x*ba[4] + ub.y*ba[5] + ub.z*ba[6] + ub.w*ba[7];
            v1 += ua.x*ba[8] + ua.y*ba[9] + ua.z*ba[10] + ua.w*ba[11]
                + ub.x*ba[12] + ub.y*ba[13] + ub.z*ba[14] + ub.w*ba[15];
            const float4* uu1 = (const float4*)&u_lds[(b * M_SEQ + m0 + 1) * CDIM];
            float4 uc = uu1[0], ud = uu1[1];
            v1 += uc.x*ba[0] + uc.y*ba[1] + uc.z*ba[2] + uc.w*ba[3]
                + ud.x*ba[4] + ud.y*ba[5] + ud.z*ba[6] + ud.w*ba[7];
            zoutb[0][b][col] = v0;
            zoutb[1][b][col] = v1;
            z_lds[b][col] = v1;
            __builtin_nontemporal_store(v0, zpred + ((size_t)(b0 + b) * M_SEQ + m0) * 128 + col);
            __builtin_nontemporal_store(v1, zpred + ((size_t)(b0 + b) * M_SEQ + m0 + 1) * 128 + col);
        }
        __syncthreads();
    }
    // final decoder (round 31)
    if (tid < 256) {
        const int mprev = 62;
        int sb = tid >> 5, c32 = tid & 31;
        int s = sb >> 2, b = sb & 3;
        float acc = cb_lds[c32];
        const float4* z4 = (const float4*)&zoutb[s][b][0];
        const float4* c4 = (const float4*)&Ct_lds[c32 * 132];
        #pragma unroll
        for (int i = 0; i < 32; ++i) {
            float4 zv = z4[i], cv = c4[i];
            acc += zv.x*cv.x + zv.y*cv.y + zv.z*cv.z + zv.w*cv.w;
        }
        __builtin_nontemporal_store(acc,
            xpred + ((size_t)(b0 + b) * M_SEQ + (mprev + s)) * SDIM + c32);
    }
}

extern "C" void kernel_launch(void* const* d_in, const int* in_sizes, int n_in,
                              void* d_out, int out_size, void* d_ws, size_t ws_size,
                              hipStream_t stream) {
    const float* x_k    = (const float*)d_in[0];
    const float* u_seq  = (const float*)d_in[1];
    const float* x_next = (const float*)d_in[2];
    const float* w0 = (const float*)d_in[3];  const float* b0 = (const float*)d_in[4];
    const float* w1 = (const float*)d_in[5];  const float* b1 = (const float*)d_in[6];
    const float* w2 = (const float*)d_in[7];  const float* b2 = (const float*)d_in[8];
    const float* w3 = (const float*)d_in[9];  const float* b3 = (const float*)d_in[10];
    const float* A_w = (const float*)d_in[11];
    const float* B_w = (const float*)d_in[12];
    const float* C_w = (const float*)d_in[13];
    const float* C_b = (const float*)d_in[14];

    float* out    = (float*)d_out;
    float* z_pred = out;                                   // 2048*64*128
    float* x_pred = out + (size_t)NROWS_NEXT * LDIM;       // 2048*64*32
    float* z_tgt  = x_pred + (size_t)NROWS_NEXT * SDIM;    // 2048*64*128

    char* ws = (char*)d_ws;
    short* pw0 = (short*)(ws);                                     // 32 KB
    short* pw1 = (short*)(ws + 32768);                             // 512 KB
    short* pw2 = (short*)(ws + 32768 + 524288);                    // 512 KB
    short* pw3 = (short*)(ws + 32768 + 2 * 524288);                // 128 KB
    float* z_k_buf = (float*)(ws + 32768 + 2 * 524288 + 131072);   // 1 MB
    float* A2_buf  = (float*)(ws + 32768 + 2 * 524288 + 131072 + 1048576);  // 64 KB

    mm128<<<128, 128, 0, stream>>>(A_w, A_w, A2_buf);

    pack_all<<<(P_S3 + 255) / 256, 256, 0, stream>>>(w0, w1, w2, w3, pw0, pw1, pw2, pw3);

    encoder_kernel<<<NROWS_ALL / 64, 512, 0, stream>>>(
        x_next, x_k, pw0, pw1, pw2, pw3, b0, b1, b2, b3, z_tgt, z_k_buf);

    recurrence2_kernel<<<B_TOT / RR4, 512, 0, stream>>>(
        z_k_buf, u_seq, B_w, A_w, A2_buf, C_w, C_b, z_pred, x_pred);
}